// Round 3
// baseline (8114.085 us; speedup 1.0000x reference)
//
#include <hip/hip_runtime.h>
#include <cstdint>
#include <cstddef>

#define B_  2
#define C_  256
#define NH_ 8
#define DH_ 32
#define LV_ 4
#define P_  4
#define L_  6
#define F_  1024
#define N_  21760
#define M_  (B_*N_)   // 43520

// ---------------------------------------------------------------------------
// Init: concat src levels (B,C,h,w) -> X[b,n,c]; pos + level_embed -> POS
// ---------------------------------------------------------------------------
__global__ __launch_bounds__(256) void concat_init_kernel(
    const float* __restrict__ s0, const float* __restrict__ s1,
    const float* __restrict__ s2, const float* __restrict__ s3,
    const float* __restrict__ p0, const float* __restrict__ p1,
    const float* __restrict__ p2, const float* __restrict__ p3,
    const float* __restrict__ le, float* __restrict__ X, float* __restrict__ POS)
{
    int idx = blockIdx.x * 256 + threadIdx.x;   // < B*N*C
    int c = idx & 255;
    int t = idx >> 8;          // b*N + n
    int b = t / N_;
    int n = t - b * N_;
    const float* sp; const float* pp; int li, st, hw;
    if      (n < 16384){ li=0; st=0;     hw=16384; sp=s0; pp=p0; }
    else if (n < 20480){ li=1; st=16384; hw=4096;  sp=s1; pp=p1; }
    else if (n < 21504){ li=2; st=20480; hw=1024;  sp=s2; pp=p2; }
    else               { li=3; st=21504; hw=256;   sp=s3; pp=p3; }
    int pix = n - st;
    size_t so = ((size_t)b * C_ + c) * hw + pix;
    X[idx]   = sp[so];
    POS[idx] = pp[so] + le[li * C_ + c];
}

// ---------------------------------------------------------------------------
// fp32 tiled GEMM:  C[M,N] = (A (+A2))[M,K] @ B[K,N] + bias[N]  (optional ReLU)
// 64x64 tile, BK=16, 256 threads, 4x4 acc/thread
// ---------------------------------------------------------------------------
__global__ __launch_bounds__(256) void gemm_bias_kernel(
    const float* __restrict__ A, const float* __restrict__ A2,
    const float* __restrict__ Bw,
    const float* __restrict__ bias, float* __restrict__ Cout,
    int M, int Nn, int K, int doRelu)
{
    __shared__ __align__(16) float As[16][68];  // [k][m], padded
    __shared__ __align__(16) float Bs[16][64];  // [k][n]

    int tid = threadIdx.x;
    int bm = blockIdx.y * 64, bn = blockIdx.x * 64;
    int tm = tid >> 4, tn = tid & 15;
    int arow = tid >> 2, akg = (tid & 3) * 4;
    int brow = tid >> 4, bcol = (tid & 15) * 4;

    const float* Aptr  = A + (size_t)(bm + arow) * K + akg;
    const float* A2ptr = A2 ? A2 + (size_t)(bm + arow) * K + akg : nullptr;
    const float* Bptr  = Bw + (size_t)brow * Nn + bn + bcol;

    float acc[4][4];
#pragma unroll
    for (int i = 0; i < 4; i++)
#pragma unroll
        for (int j = 0; j < 4; j++) acc[i][j] = 0.f;

    for (int k0 = 0; k0 < K; k0 += 16) {
        float4 av = *(const float4*)(Aptr + k0);
        if (A2ptr) {
            float4 a2 = *(const float4*)(A2ptr + k0);
            av.x += a2.x; av.y += a2.y; av.z += a2.z; av.w += a2.w;
        }
        float4 bv = *(const float4*)(Bptr + (size_t)k0 * Nn);
        __syncthreads();
        As[akg+0][arow] = av.x; As[akg+1][arow] = av.y;
        As[akg+2][arow] = av.z; As[akg+3][arow] = av.w;
        *(float4*)&Bs[brow][bcol] = bv;
        __syncthreads();
#pragma unroll
        for (int k = 0; k < 16; k++) {
            float4 a4 = *(const float4*)&As[k][tm * 4];
            float4 b4 = *(const float4*)&Bs[k][tn * 4];
            float ar[4] = {a4.x, a4.y, a4.z, a4.w};
            float br[4] = {b4.x, b4.y, b4.z, b4.w};
#pragma unroll
            for (int i = 0; i < 4; i++)
#pragma unroll
                for (int j = 0; j < 4; j++) acc[i][j] += ar[i] * br[j];
        }
    }

    float4 bb = *(const float4*)(bias + bn + tn * 4);
#pragma unroll
    for (int i = 0; i < 4; i++) {
        int row = bm + tm * 4 + i;
        float4 o;
        o.x = acc[i][0] + bb.x; o.y = acc[i][1] + bb.y;
        o.z = acc[i][2] + bb.z; o.w = acc[i][3] + bb.w;
        if (doRelu) {
            o.x = fmaxf(o.x, 0.f); o.y = fmaxf(o.y, 0.f);
            o.z = fmaxf(o.z, 0.f); o.w = fmaxf(o.w, 0.f);
        }
        *(float4*)(Cout + (size_t)row * Nn + bn + tn * 4) = o;
    }
}

// ---------------------------------------------------------------------------
// x = LayerNorm(x + res) * g + b   — one wave per row of 256
// ---------------------------------------------------------------------------
__global__ __launch_bounds__(256) void ln_residual_kernel(
    float* __restrict__ x, const float* __restrict__ res,
    const float* __restrict__ g, const float* __restrict__ bta)
{
    int row  = blockIdx.x * 4 + (threadIdx.x >> 6);
    int lane = threadIdx.x & 63;
    float* xr = x + (size_t)row * C_ + lane * 4;
    const float* rr = res + (size_t)row * C_ + lane * 4;
    float4 xv = *(const float4*)xr;
    float4 rv = *(const float4*)rr;
    float v0 = xv.x + rv.x, v1 = xv.y + rv.y, v2 = xv.z + rv.z, v3 = xv.w + rv.w;
    float s  = v0 + v1 + v2 + v3;
    float s2 = v0*v0 + v1*v1 + v2*v2 + v3*v3;
#pragma unroll
    for (int off = 1; off < 64; off <<= 1) {
        s  += __shfl_xor(s,  off, 64);
        s2 += __shfl_xor(s2, off, 64);
    }
    float mu  = s * (1.f / C_);
    float var = s2 * (1.f / C_) - mu * mu;
    float rs  = rsqrtf(var + 1e-5f);
    float4 gv = *(const float4*)(g + lane * 4);
    float4 bv = *(const float4*)(bta + lane * 4);
    float4 o;
    o.x = (v0 - mu) * rs * gv.x + bv.x;
    o.y = (v1 - mu) * rs * gv.y + bv.y;
    o.z = (v2 - mu) * rs * gv.z + bv.z;
    o.w = (v3 - mu) * rs * gv.w + bv.w;
    *(float4*)xr = o;
}

// ---------------------------------------------------------------------------
// Deformable sampling: one block per (b,n); 256 threads = 8 heads x 32 dims
// ---------------------------------------------------------------------------
__device__ __forceinline__ float corner_load(const float* vb, int xi, int yi,
                                             int wl, int hl, int st)
{
    bool valid = (xi >= 0) & (xi < wl) & (yi >= 0) & (yi < hl);
    int xc = min(max(xi, 0), wl - 1);
    int yc = min(max(yi, 0), hl - 1);
    float v = vb[(size_t)(st + yc * wl + xc) * C_];
    return valid ? v : 0.f;
}

__global__ __launch_bounds__(256) void msdeform_kernel(
    const float* __restrict__ VAL, const float* __restrict__ OFF,
    const float* __restrict__ ATT, float* __restrict__ SAMP)
{
    int bn = blockIdx.x;
    int b = bn / N_;
    int n = bn - b * N_;
    int tid = threadIdx.x;
    int head = tid >> 5, d = tid & 31;

    __shared__ float s_att[NH_ * 16];
    __shared__ float s_off[NH_ * 16 * 2];
    if (tid < 128) s_att[tid] = ATT[(size_t)bn * 128 + tid];
    s_off[tid] = OFF[(size_t)bn * 256 + tid];
    __syncthreads();

    // softmax over this head's 16 logits (redundant across 32 lanes — cheap)
    float m = -1e30f;
#pragma unroll
    for (int i = 0; i < 16; i++) m = fmaxf(m, s_att[head * 16 + i]);
    float ssum = 0.f;
#pragma unroll
    for (int i = 0; i < 16; i++) ssum += __expf(s_att[head * 16 + i] - m);
    float sinv = 1.f / ssum;

    // reference point of query n (its own level's grid center)
    int wq, hq, sq;
    if      (n < 16384){ sq = 0;     hq = 128; wq = 128; }
    else if (n < 20480){ sq = 16384; hq = 64;  wq = 64;  }
    else if (n < 21504){ sq = 20480; hq = 32;  wq = 32;  }
    else               { sq = 21504; hq = 16;  wq = 16;  }
    int pidx = n - sq;
    int prow = pidx / wq, pcol = pidx & (wq - 1);
    float refx = (pcol + 0.5f) / wq;
    float refy = (prow + 0.5f) / hq;

    const int HS[4] = {128, 64, 32, 16};
    const int ST[4] = {0, 16384, 20480, 21504};

    const float* vbase = VAL + (size_t)b * N_ * C_ + head * DH_ + d;
    float acc = 0.f;
#pragma unroll
    for (int li = 0; li < LV_; li++) {
        int hl = HS[li], wl = HS[li], st = ST[li];
        float fw = (float)wl, fh = (float)hl;
#pragma unroll
        for (int p = 0; p < P_; p++) {
            int idx = head * 16 + li * 4 + p;
            float ax = s_off[idx * 2 + 0], ay = s_off[idx * 2 + 1];
            float aw = __expf(s_att[idx] - m) * sinv;
            float xx = (refx + ax / fw) * fw - 0.5f;
            float yy = (refy + ay / fh) * fh - 0.5f;
            float xf = floorf(xx), yf = floorf(yy);
            float wx = xx - xf, wy = yy - yf;
            int x0 = (int)xf, y0 = (int)yf;
            float v00 = corner_load(vbase, x0,     y0,     wl, hl, st);
            float v01 = corner_load(vbase, x0 + 1, y0,     wl, hl, st);
            float v10 = corner_load(vbase, x0,     y0 + 1, wl, hl, st);
            float v11 = corner_load(vbase, x0 + 1, y0 + 1, wl, hl, st);
            float sampv = v00 * (1.f - wx) * (1.f - wy) + v01 * wx * (1.f - wy)
                        + v10 * (1.f - wx) * wy         + v11 * wx * wy;
            acc += aw * sampv;
        }
    }
    SAMP[(size_t)bn * C_ + tid] = acc;
}

// ---------------------------------------------------------------------------
// Workspace (floats):  POS | VAL | OFF | SAMP | ATT(SZ/2)   = 4.5*SZ
//   = 200,540,160 bytes.  VAL doubles as the FFN hidden chunk
//   (10880 x 1024 = SZ floats exactly); OFF doubles as attn-out.
// ---------------------------------------------------------------------------
extern "C" void kernel_launch(void* const* d_in, const int* in_sizes, int n_in,
                              void* d_out, int out_size, void* d_ws, size_t ws_size,
                              hipStream_t stream)
{
    // setup_inputs() dict order is INTERLEAVED: src0,pos0,src1,pos1,...
    // (the i-loop inserts srcI then posI). Detect defensively via sizes:
    // interleaved => in_sizes[1]==in_sizes[0] (pos0, 8.4M); grouped => src1 (2.1M).
    const float *srcs[4], *poss[4];
    if (in_sizes[1] == in_sizes[0]) {
        srcs[0] = (const float*)d_in[0]; poss[0] = (const float*)d_in[1];
        srcs[1] = (const float*)d_in[2]; poss[1] = (const float*)d_in[3];
        srcs[2] = (const float*)d_in[4]; poss[2] = (const float*)d_in[5];
        srcs[3] = (const float*)d_in[6]; poss[3] = (const float*)d_in[7];
    } else {
        srcs[0] = (const float*)d_in[0]; srcs[1] = (const float*)d_in[1];
        srcs[2] = (const float*)d_in[2]; srcs[3] = (const float*)d_in[3];
        poss[0] = (const float*)d_in[4]; poss[1] = (const float*)d_in[5];
        poss[2] = (const float*)d_in[6]; poss[3] = (const float*)d_in[7];
    }
    const float* le = (const float*)d_in[8];

    float* X = (float*)d_out;                       // x lives in d_out
    const size_t SZ = (size_t)M_ * C_;              // 11,141,120 floats
    float* POS  = (float*)d_ws;                     // persists all layers
    float* VAL  = POS  + SZ;                        // value / FFN hidden chunk
    float* OFF  = VAL  + SZ;                        // offsets / attn-out
    float* SAMP = OFF  + SZ;                        // sampled attn / FFN out
    float* ATT  = SAMP + SZ;                        // B*N*128

    concat_init_kernel<<<M_, 256, 0, stream>>>(srcs[0], srcs[1], srcs[2], srcs[3],
                                               poss[0], poss[1], poss[2], poss[3],
                                               le, X, POS);

    const int MCH = M_ / 4;                         // 10880-row FFN chunks

    for (int l = 0; l < L_; l++) {
        const float* Woff = (const float*)d_in[9]  + (size_t)l * C_ * 256;
        const float* boff = (const float*)d_in[10] + (size_t)l * 256;
        const float* Watt = (const float*)d_in[11] + (size_t)l * C_ * 128;
        const float* batt = (const float*)d_in[12] + (size_t)l * 128;
        const float* Wval = (const float*)d_in[13] + (size_t)l * C_ * C_;
        const float* bval = (const float*)d_in[14] + (size_t)l * C_;
        const float* Wout = (const float*)d_in[15] + (size_t)l * C_ * C_;
        const float* bout = (const float*)d_in[16] + (size_t)l * C_;
        const float* g1   = (const float*)d_in[17] + (size_t)l * C_;
        const float* b1   = (const float*)d_in[18] + (size_t)l * C_;
        const float* Wf1  = (const float*)d_in[19] + (size_t)l * C_ * F_;
        const float* bf1  = (const float*)d_in[20] + (size_t)l * F_;
        const float* Wf2  = (const float*)d_in[21] + (size_t)l * F_ * C_;
        const float* bf2  = (const float*)d_in[22] + (size_t)l * C_;
        const float* g2   = (const float*)d_in[23] + (size_t)l * C_;
        const float* b2   = (const float*)d_in[24] + (size_t)l * C_;

        // value / offset / attn projections (q = x + pos fused via A2)
        gemm_bias_kernel<<<dim3(4, M_/64), 256, 0, stream>>>(X, nullptr, Wval, bval, VAL, M_, 256, 256, 0);
        gemm_bias_kernel<<<dim3(4, M_/64), 256, 0, stream>>>(X, POS,     Woff, boff, OFF, M_, 256, 256, 0);
        gemm_bias_kernel<<<dim3(2, M_/64), 256, 0, stream>>>(X, POS,     Watt, batt, ATT, M_, 128, 256, 0);
        msdeform_kernel<<<M_, 256, 0, stream>>>(VAL, OFF, ATT, SAMP);
        // output projection -> OFF (dead after sampling)
        gemm_bias_kernel<<<dim3(4, M_/64), 256, 0, stream>>>(SAMP, nullptr, Wout, bout, OFF, M_, 256, 256, 0);
        ln_residual_kernel<<<M_/4, 256, 0, stream>>>(X, OFF, g1, b1);

        // FFN, chunked so hidden (chunk x 1024) fits in VAL (dead after sampling)
        for (int c = 0; c < 4; c++) {
            const float* Xc = X + (size_t)c * MCH * C_;
            float* Yc = SAMP + (size_t)c * MCH * C_;
            gemm_bias_kernel<<<dim3(16, MCH/64), 256, 0, stream>>>(Xc,  nullptr, Wf1, bf1, VAL, MCH, 1024, 256,  1);
            gemm_bias_kernel<<<dim3(4,  MCH/64), 256, 0, stream>>>(VAL, nullptr, Wf2, bf2, Yc,  MCH, 256,  1024, 0);
        }
        ln_residual_kernel<<<M_/4, 256, 0, stream>>>(X, SAMP, g2, b2);
    }
}

// Round 4
// 2167.842 us; speedup vs baseline: 3.7429x; 3.7429x over previous
//
#include <hip/hip_runtime.h>
#include <cstdint>
#include <cstddef>

#define B_  2
#define C_  256
#define NH_ 8
#define LV_ 4
#define P_  4
#define L_  6
#define F_  1024
#define N_  21760
#define M_  (B_*N_)   // 43520

typedef unsigned short ushort_t;
typedef __attribute__((ext_vector_type(8))) short bf16x8;
typedef __attribute__((ext_vector_type(4))) float f32x4;

__device__ __forceinline__ float b2f(ushort_t u){
    union { unsigned int i; float f; } v; v.i = ((unsigned int)u) << 16; return v.f;
}
__device__ __forceinline__ ushort_t f2b(float f){
    union { float f; unsigned int i; } v; v.f = f;
    return (ushort_t)((v.i + 0x7fffu + ((v.i >> 16) & 1u)) >> 16);
}

// async global->LDS, 16B per lane, dst = wave-uniform base + lane*16
__device__ __forceinline__ void gload16(const void* g, void* l){
    __builtin_amdgcn_global_load_lds(
        (const __attribute__((address_space(1))) unsigned int*)g,
        (__attribute__((address_space(3))) unsigned int*)l, 16, 0, 0);
}

// ---------------------------------------------------------------------------
// Init: concat src levels -> X[b,n,c] (fp32) + Xb (bf16); pos+levemb -> POS, Qb
// ---------------------------------------------------------------------------
__global__ __launch_bounds__(256) void concat_init_kernel(
    const float* __restrict__ s0, const float* __restrict__ s1,
    const float* __restrict__ s2, const float* __restrict__ s3,
    const float* __restrict__ p0, const float* __restrict__ p1,
    const float* __restrict__ p2, const float* __restrict__ p3,
    const float* __restrict__ le, float* __restrict__ X, float* __restrict__ POS,
    ushort_t* __restrict__ Xb, ushort_t* __restrict__ Qb)
{
    int idx = blockIdx.x * 256 + threadIdx.x;
    int c = idx & 255;
    int t = idx >> 8;
    int b = t / N_;
    int n = t - b * N_;
    const float* sp; const float* pp; int li, st, hw;
    if      (n < 16384){ li=0; st=0;     hw=16384; sp=s0; pp=p0; }
    else if (n < 20480){ li=1; st=16384; hw=4096;  sp=s1; pp=p1; }
    else if (n < 21504){ li=2; st=20480; hw=1024;  sp=s2; pp=p2; }
    else               { li=3; st=21504; hw=256;   sp=s3; pp=p3; }
    int pix = n - st;
    size_t so = ((size_t)b * C_ + c) * hw + pix;
    float xv = sp[so];
    float pv = pp[so] + le[li * C_ + c];
    X[idx]   = xv;
    POS[idx] = pv;
    Xb[idx]  = f2b(xv);
    Qb[idx]  = f2b(xv + pv);
}

// ---------------------------------------------------------------------------
// Weight prep: fp32 [L][K][N] -> bf16 [l*outStride + n*K + k]  (transpose+cast)
// ---------------------------------------------------------------------------
__global__ __launch_bounds__(256) void wprep_kernel(
    const float* __restrict__ in, ushort_t* __restrict__ out,
    int K, int Nn, long outLayerStride)
{
    int idx = blockIdx.x * 256 + threadIdx.x;     // < L*K*N
    int per = K * Nn;
    int l   = idx / per;
    int rem = idx - l * per;
    int k   = rem / Nn;
    int nn  = rem - k * Nn;
    out[(long)l * outLayerStride + (long)nn * K + k] = f2b(in[idx]);
}

// ---------------------------------------------------------------------------
// bf16 MFMA GEMM: C[M,N] = A[M,K](bf16) @ BT[N,K](bf16)^T + bias (fp32)
// 128x128 tile, BK=32, 256 thr = 4 waves (2x2 of 64x64), 16x16x32 MFMA
// output fp32 (Cf) or bf16 (Cb), optional relu
// ---------------------------------------------------------------------------
__global__ __launch_bounds__(256) void gemm_bf16_kernel(
    const ushort_t* __restrict__ A, const ushort_t* __restrict__ BT,
    const float* __restrict__ bias,
    float* __restrict__ Cf, ushort_t* __restrict__ Cb,
    int M, int Nn, int K, int relu)
{
    __shared__ ushort_t Alds[128*32];
    __shared__ ushort_t Blds[128*32];
    const int tid  = threadIdx.x;
    const int wave = tid >> 6, lane = tid & 63;
    const int bm = blockIdx.y * 128, bn = blockIdx.x * 128;
    const int wm = (wave >> 1) * 64, wn = (wave & 1) * 64;

    // staging: 8 chunks of 1024B per tile; wave handles chunks 2w, 2w+1
    const int c0 = wave * 2, c1 = wave * 2 + 1;
    const int rIn = lane >> 2;          // row within 16-row chunk
    const int cIn = (lane & 3) * 8;     // k-offset (8 bf16 = 16B)
    const ushort_t* Ag0 = A  + (size_t)(bm + c0*16 + rIn) * K + cIn;
    const ushort_t* Ag1 = A  + (size_t)(bm + c1*16 + rIn) * K + cIn;
    const ushort_t* Bg0 = BT + (size_t)(bn + c0*16 + rIn) * K + cIn;
    const ushort_t* Bg1 = BT + (size_t)(bn + c1*16 + rIn) * K + cIn;
    ushort_t* Al0 = &Alds[c0 * 512]; ushort_t* Al1 = &Alds[c1 * 512];
    ushort_t* Bl0 = &Blds[c0 * 512]; ushort_t* Bl1 = &Blds[c1 * 512];

    const int fm    = lane & 15;
    const int quad8 = (lane >> 4) * 8;

    f32x4 acc[4][4];
#pragma unroll
    for (int i = 0; i < 4; i++)
#pragma unroll
        for (int j = 0; j < 4; j++) acc[i][j] = (f32x4){0.f,0.f,0.f,0.f};

    for (int k0 = 0; k0 < K; k0 += 32) {
        gload16(Ag0 + k0, Al0);
        gload16(Ag1 + k0, Al1);
        gload16(Bg0 + k0, Bl0);
        gload16(Bg1 + k0, Bl1);
        __syncthreads();                 // drains vmcnt before barrier
        bf16x8 af[4], bfr[4];
#pragma unroll
        for (int i = 0; i < 4; i++)
            af[i]  = *(const bf16x8*)&Alds[(wm + i*16 + fm) * 32 + quad8];
#pragma unroll
        for (int j = 0; j < 4; j++)
            bfr[j] = *(const bf16x8*)&Blds[(wn + j*16 + fm) * 32 + quad8];
#pragma unroll
        for (int i = 0; i < 4; i++)
#pragma unroll
            for (int j = 0; j < 4; j++)
                acc[i][j] = __builtin_amdgcn_mfma_f32_16x16x32_bf16(af[i], bfr[j], acc[i][j], 0, 0, 0);
        __syncthreads();                 // protect LDS before next stage
    }

    const int rq = (lane >> 4) * 4;
#pragma unroll
    for (int j = 0; j < 4; j++) {
        int col = bn + wn + j*16 + fm;
        float bb = bias[col];
#pragma unroll
        for (int i = 0; i < 4; i++) {
            int row0 = bm + wm + i*16 + rq;
#pragma unroll
            for (int r = 0; r < 4; r++) {
                float v = acc[i][j][r] + bb;
                if (relu) v = fmaxf(v, 0.f);
                if (Cf) Cf[(size_t)(row0 + r) * Nn + col] = v;
                else    Cb[(size_t)(row0 + r) * Nn + col] = f2b(v);
            }
        }
    }
}

// ---------------------------------------------------------------------------
// x = LN(x + res_bf16)*g + b; writes X fp32, Xb bf16, optional Qb = bf16(x+pos)
// ---------------------------------------------------------------------------
__global__ __launch_bounds__(256) void ln_residual_kernel(
    float* __restrict__ x, const ushort_t* __restrict__ res,
    const float* __restrict__ g, const float* __restrict__ bta,
    ushort_t* __restrict__ xb, const float* __restrict__ pos,
    ushort_t* __restrict__ qb)
{
    int row  = blockIdx.x * 4 + (threadIdx.x >> 6);
    int lane = threadIdx.x & 63;
    size_t base = (size_t)row * C_ + lane * 4;
    float4  xv = *(const float4*)(x + base);
    ushort4 rv = *(const ushort4*)(res + base);
    float v0 = xv.x + b2f(rv.x), v1 = xv.y + b2f(rv.y);
    float v2 = xv.z + b2f(rv.z), v3 = xv.w + b2f(rv.w);
    float s  = v0 + v1 + v2 + v3;
    float s2 = v0*v0 + v1*v1 + v2*v2 + v3*v3;
#pragma unroll
    for (int off = 1; off < 64; off <<= 1) {
        s  += __shfl_xor(s,  off, 64);
        s2 += __shfl_xor(s2, off, 64);
    }
    float mu  = s * (1.f / C_);
    float var = s2 * (1.f / C_) - mu * mu;
    float rs  = rsqrtf(var + 1e-5f);
    float4 gv = *(const float4*)(g + lane * 4);
    float4 bv = *(const float4*)(bta + lane * 4);
    float4 o;
    o.x = (v0 - mu) * rs * gv.x + bv.x;
    o.y = (v1 - mu) * rs * gv.y + bv.y;
    o.z = (v2 - mu) * rs * gv.z + bv.z;
    o.w = (v3 - mu) * rs * gv.w + bv.w;
    *(float4*)(x + base) = o;
    ushort4 ob; ob.x = f2b(o.x); ob.y = f2b(o.y); ob.z = f2b(o.z); ob.w = f2b(o.w);
    *(ushort4*)(xb + base) = ob;
    if (qb) {
        float4 pv = *(const float4*)(pos + base);
        ushort4 qv;
        qv.x = f2b(o.x + pv.x); qv.y = f2b(o.y + pv.y);
        qv.z = f2b(o.z + pv.z); qv.w = f2b(o.w + pv.w);
        *(ushort4*)(qb + base) = qv;
    }
}

// ---------------------------------------------------------------------------
// Deformable sampling, 2-phase. Block = 128 thr per query.
// Phase 1: thread = (head,pt): softmax + fold attn*bilinear*valid into
//          4 weights + 4 byte-offsets in LDS.
// Phase 2: thread = (head, dim-pair): 64 gathers of bf16x2.
// ---------------------------------------------------------------------------
__global__ __launch_bounds__(128) void msdeform_kernel(
    const ushort_t* __restrict__ VALb, const float* __restrict__ OFF,
    const float* __restrict__ ATT, ushort_t* __restrict__ SAMPb)
{
    const int bn = blockIdx.x;
    const int b = bn / N_;
    const int n = bn - b * N_;
    const int tid = threadIdx.x;

    __shared__ int   s_idx[128 * 4];
    __shared__ float s_w[128 * 4];

    {   // phase 1 — task index == tid (head = tid>>4, li = (tid>>2)&3, p = tid&3)
        const int head = tid >> 4, li = (tid >> 2) & 3;
        float logit = ATT[(size_t)bn * 128 + tid];
        float ox = OFF[(size_t)bn * 256 + tid * 2 + 0];
        float oy = OFF[(size_t)bn * 256 + tid * 2 + 1];
        float mx = logit;
#pragma unroll
        for (int s = 1; s < 16; s <<= 1) mx = fmaxf(mx, __shfl_xor(mx, s, 16));
        float e = __expf(logit - mx), sm = e;
#pragma unroll
        for (int s = 1; s < 16; s <<= 1) sm += __shfl_xor(sm, s, 16);
        float aw = e / sm;

        int sq, lwq;
        if      (n < 16384){ sq = 0;     lwq = 7; }
        else if (n < 20480){ sq = 16384; lwq = 6; }
        else if (n < 21504){ sq = 20480; lwq = 5; }
        else               { sq = 21504; lwq = 4; }
        int pidx = n - sq;
        int prow = pidx >> lwq, pcol = pidx & ((1 << lwq) - 1);
        float inv = 1.f / (float)(1 << lwq);
        float refx = (pcol + 0.5f) * inv;
        float refy = (prow + 0.5f) * inv;

        const int HS[4] = {128, 64, 32, 16};
        const int ST[4] = {0, 16384, 20480, 21504};
        int wl = HS[li], st = ST[li];
        float fw = (float)wl;
        float xx = refx * fw + ox - 0.5f;   // (refx + ox/w)*w - 0.5
        float yy = refy * fw + oy - 0.5f;
        float xf = floorf(xx), yf = floorf(yy);
        float wx = xx - xf, wy = yy - yf;
        int x0 = (int)xf, y0 = (int)yf;
#pragma unroll
        for (int c2 = 0; c2 < 4; c2++) {
            int dx = c2 & 1, dy = c2 >> 1;
            int xi = x0 + dx, yi = y0 + dy;
            float wgt = (dx ? wx : 1.f - wx) * (dy ? wy : 1.f - wy);
            bool valid = (xi >= 0) & (xi < wl) & (yi >= 0) & (yi < wl);
            int xc = min(max(xi, 0), wl - 1), yc = min(max(yi, 0), wl - 1);
            s_idx[tid * 4 + c2] = ((st + yc * wl + xc) * C_ + head * 32) * 2;  // bytes
            s_w[tid * 4 + c2]   = valid ? aw * wgt : 0.f;
        }
    }
    __syncthreads();

    const int head = tid >> 4, e2 = (tid & 15) * 2;
    const char* vb = (const char*)VALb + ((size_t)b * N_ * C_ + e2) * 2;
    const int base2 = head * 64;
    float a0 = 0.f, a1 = 0.f;
#pragma unroll 8
    for (int j = 0; j < 64; j++) {
        float w   = s_w[base2 + j];
        int   off = s_idx[base2 + j];
        ushort2 u = *(const ushort2*)(vb + off);
        a0 += w * b2f(u.x);
        a1 += w * b2f(u.y);
    }
    ushort2 o2; o2.x = f2b(a0); o2.y = f2b(a1);
    *(ushort2*)(SAMPb + (size_t)bn * C_ + head * 32 + e2) = o2;
}

// ---------------------------------------------------------------------------
// Workspace layout (bytes), total 209,584,128:
//   POS f32 44.56M | OFF f32 44.56M | ATT f32 22.28M | SAMPb bf16 22.28M |
//   VALb bf16 22.28M | Xb 22.28M | Qb 22.28M | WT bf16 9.04M
//   FFN hidden Hb (bf16, M*1024 = 89,128,960 B) overlays [OFF|ATT|SAMPb].
//   VALb region also hosts attn-out and FFN-out (both bf16, dead-time reuse).
// ---------------------------------------------------------------------------
extern "C" void kernel_launch(void* const* d_in, const int* in_sizes, int n_in,
                              void* d_out, int out_size, void* d_ws, size_t ws_size,
                              hipStream_t stream)
{
    const float *srcs[4], *poss[4];
    if (in_sizes[1] == in_sizes[0]) {   // interleaved src0,pos0,src1,pos1,...
        srcs[0] = (const float*)d_in[0]; poss[0] = (const float*)d_in[1];
        srcs[1] = (const float*)d_in[2]; poss[1] = (const float*)d_in[3];
        srcs[2] = (const float*)d_in[4]; poss[2] = (const float*)d_in[5];
        srcs[3] = (const float*)d_in[6]; poss[3] = (const float*)d_in[7];
    } else {
        srcs[0] = (const float*)d_in[0]; srcs[1] = (const float*)d_in[1];
        srcs[2] = (const float*)d_in[2]; srcs[3] = (const float*)d_in[3];
        poss[0] = (const float*)d_in[4]; poss[1] = (const float*)d_in[5];
        poss[2] = (const float*)d_in[6]; poss[3] = (const float*)d_in[7];
    }
    const float* le = (const float*)d_in[8];

    float* X = (float*)d_out;
    char* w = (char*)d_ws;
    float*    POS   = (float*)w;              w += (size_t)M_ * C_ * 4;
    float*    OFFf  = (float*)w;              w += (size_t)M_ * C_ * 4;
    float*    ATTf  = (float*)w;              w += (size_t)M_ * 128 * 4;
    ushort_t* SAMPB = (ushort_t*)w;           w += (size_t)M_ * C_ * 2;
    ushort_t* VALB  = (ushort_t*)w;           w += (size_t)M_ * C_ * 2;
    ushort_t* XB    = (ushort_t*)w;           w += (size_t)M_ * C_ * 2;
    ushort_t* QB    = (ushort_t*)w;           w += (size_t)M_ * C_ * 2;
    ushort_t* WT    = (ushort_t*)w;
    ushort_t* HB    = (ushort_t*)OFFf;        // overlays OFF|ATT|SAMPb exactly

    // per-layer WT element offsets
    const long LSTRIDE = 753664;
    const long O_WVAL = 0, O_WOFF = 65536, O_WATT = 131072, O_WOUT = 163840,
               O_WF1 = 229376, O_WF2 = 491520;

    // weight prep (transpose + cast), 6 launches
    wprep_kernel<<<6*65536/256, 256, 0, stream>>>((const float*)d_in[13], WT + O_WVAL, 256, 256,  LSTRIDE);
    wprep_kernel<<<6*65536/256, 256, 0, stream>>>((const float*)d_in[9],  WT + O_WOFF, 256, 256,  LSTRIDE);
    wprep_kernel<<<6*32768/256, 256, 0, stream>>>((const float*)d_in[11], WT + O_WATT, 256, 128,  LSTRIDE);
    wprep_kernel<<<6*65536/256, 256, 0, stream>>>((const float*)d_in[15], WT + O_WOUT, 256, 256,  LSTRIDE);
    wprep_kernel<<<6*262144/256,256, 0, stream>>>((const float*)d_in[19], WT + O_WF1,  256, 1024, LSTRIDE);
    wprep_kernel<<<6*262144/256,256, 0, stream>>>((const float*)d_in[21], WT + O_WF2,  1024, 256, LSTRIDE);

    concat_init_kernel<<<M_, 256, 0, stream>>>(srcs[0], srcs[1], srcs[2], srcs[3],
                                               poss[0], poss[1], poss[2], poss[3],
                                               le, X, POS, XB, QB);

    for (int l = 0; l < L_; l++) {
        const ushort_t* wt = WT + (size_t)l * LSTRIDE;
        const float* boff = (const float*)d_in[10] + (size_t)l * 256;
        const float* batt = (const float*)d_in[12] + (size_t)l * 128;
        const float* bval = (const float*)d_in[14] + (size_t)l * C_;
        const float* bout = (const float*)d_in[16] + (size_t)l * C_;
        const float* g1   = (const float*)d_in[17] + (size_t)l * C_;
        const float* b1   = (const float*)d_in[18] + (size_t)l * C_;
        const float* bf1  = (const float*)d_in[20] + (size_t)l * F_;
        const float* bf2  = (const float*)d_in[22] + (size_t)l * C_;
        const float* g2   = (const float*)d_in[23] + (size_t)l * C_;
        const float* b2   = (const float*)d_in[24] + (size_t)l * C_;

        gemm_bf16_kernel<<<dim3(2, M_/128), 256, 0, stream>>>(XB, wt + O_WVAL, bval, nullptr, VALB, M_, 256, 256, 0);
        gemm_bf16_kernel<<<dim3(2, M_/128), 256, 0, stream>>>(QB, wt + O_WOFF, boff, OFFf,  nullptr, M_, 256, 256, 0);
        gemm_bf16_kernel<<<dim3(1, M_/128), 256, 0, stream>>>(QB, wt + O_WATT, batt, ATTf,  nullptr, M_, 128, 256, 0);
        msdeform_kernel<<<M_, 128, 0, stream>>>(VALB, OFFf, ATTf, SAMPB);
        gemm_bf16_kernel<<<dim3(2, M_/128), 256, 0, stream>>>(SAMPB, wt + O_WOUT, bout, nullptr, VALB, M_, 256, 256, 0);
        ln_residual_kernel<<<M_/4, 256, 0, stream>>>(X, VALB, g1, b1, XB, nullptr, nullptr);
        gemm_bf16_kernel<<<dim3(8, M_/128), 256, 0, stream>>>(XB, wt + O_WF1, bf1, nullptr, HB,   M_, 1024, 256,  1);
        gemm_bf16_kernel<<<dim3(2, M_/128), 256, 0, stream>>>(HB, wt + O_WF2, bf2, nullptr, VALB, M_, 256,  1024, 0);
        ln_residual_kernel<<<M_/4, 256, 0, stream>>>(X, VALB, g2, b2, XB, POS, QB);
    }
}

// Round 5
// 2029.775 us; speedup vs baseline: 3.9975x; 1.0680x over previous
//
#include <hip/hip_runtime.h>
#include <cstdint>
#include <cstddef>

#define B_  2
#define C_  256
#define NH_ 8
#define LV_ 4
#define P_  4
#define L_  6
#define F_  1024
#define N_  21760
#define M_  (B_*N_)   // 43520

typedef unsigned short ushort_t;
typedef __attribute__((ext_vector_type(8))) short bf16x8;
typedef __attribute__((ext_vector_type(4))) float f32x4;

__device__ __forceinline__ float b2f(ushort_t u){
    union { unsigned int i; float f; } v; v.i = ((unsigned int)u) << 16; return v.f;
}
__device__ __forceinline__ ushort_t f2b(float f){
    union { float f; unsigned int i; } v; v.f = f;
    return (ushort_t)((v.i + 0x7fffu + ((v.i >> 16) & 1u)) >> 16);
}

// async global->LDS, 16B per lane, dst = wave-uniform base + lane*16
__device__ __forceinline__ void gload16(const void* g, void* l){
    __builtin_amdgcn_global_load_lds(
        (const __attribute__((address_space(1))) unsigned int*)g,
        (__attribute__((address_space(3))) unsigned int*)l, 16, 0, 0);
}

// ---------------------------------------------------------------------------
// Coalesced concat+transpose init. Block = one 32x32 tile of one (b,level).
// Reads coalesced along pix, writes coalesced along c via LDS transpose.
// Emits X fp32, XB bf16, QB bf16(x+pos), POSB bf16.
// Tiles per b: lvl0 512x8=4096, lvl1 128x8=1024, lvl2 32x8=256, lvl3 8x8=64
//   => 5440 per b, 10880 total.
// ---------------------------------------------------------------------------
__global__ __launch_bounds__(256) void concat_init_kernel(
    const float* __restrict__ s0, const float* __restrict__ s1,
    const float* __restrict__ s2, const float* __restrict__ s3,
    const float* __restrict__ p0, const float* __restrict__ p1,
    const float* __restrict__ p2, const float* __restrict__ p3,
    const float* __restrict__ le, float* __restrict__ X,
    ushort_t* __restrict__ POSB, ushort_t* __restrict__ XB,
    ushort_t* __restrict__ QB)
{
    int bid = blockIdx.x;
    int b = bid / 5440;
    int r = bid - b * 5440;
    const float* sp; const float* pp; int li, st, hw, t;
    if      (r < 4096){ li=0; st=0;     hw=16384; t=r;        sp=s0; pp=p0; }
    else if (r < 5120){ li=1; st=16384; hw=4096;  t=r-4096;   sp=s1; pp=p1; }
    else if (r < 5376){ li=2; st=20480; hw=1024;  t=r-5120;   sp=s2; pp=p2; }
    else              { li=3; st=21504; hw=256;   t=r-5376;   sp=s3; pp=p3; }
    int pt = t >> 3, ct = t & 7;   // pix-tile, c-tile (C/32 = 8)

    __shared__ float ts[32][33], tp[32][33];
    int tx  = threadIdx.x & 31;
    int ty8 = threadIdx.x >> 5;    // 0..7
#pragma unroll
    for (int i = 0; i < 4; i++) {
        int c   = ct * 32 + ty8 + i * 8;
        int pix = pt * 32 + tx;
        size_t so = ((size_t)b * C_ + c) * hw + pix;
        ts[ty8 + i * 8][tx] = sp[so];
        tp[ty8 + i * 8][tx] = pp[so];
    }
    __syncthreads();
#pragma unroll
    for (int i = 0; i < 4; i++) {
        int cw = tx, pw = ty8 + i * 8;
        int c = ct * 32 + cw;
        int n = st + pt * 32 + pw;
        size_t o = ((size_t)b * N_ + n) * C_ + c;
        float xv = ts[cw][pw];
        float pv = tp[cw][pw] + le[li * C_ + c];
        X[o]    = xv;
        XB[o]   = f2b(xv);
        POSB[o] = f2b(pv);
        QB[o]   = f2b(xv + pv);
    }
}

// ---------------------------------------------------------------------------
// Weight prep: fp32 [L][K][N] -> bf16 [l*outStride + n*K + k]  (transpose+cast)
// ---------------------------------------------------------------------------
__global__ __launch_bounds__(256) void wprep_kernel(
    const float* __restrict__ in, ushort_t* __restrict__ out,
    int K, int Nn, long outLayerStride)
{
    int idx = blockIdx.x * 256 + threadIdx.x;     // < L*K*N
    int per = K * Nn;
    int l   = idx / per;
    int rem = idx - l * per;
    int k   = rem / Nn;
    int nn  = rem - k * Nn;
    out[(long)l * outLayerStride + (long)nn * K + k] = f2b(in[idx]);
}

// packed bias for fused off+att GEMM: pb[l][0:256]=boff, [256:384]=batt
__global__ __launch_bounds__(256) void bias_pack_kernel(
    const float* __restrict__ boff, const float* __restrict__ batt,
    float* __restrict__ pb)
{
    int i = blockIdx.x * 256 + threadIdx.x;       // < 6*384
    if (i >= 6 * 384) return;
    int l = i / 384, j = i - l * 384;
    pb[i] = (j < 256) ? boff[l * 256 + j] : batt[l * 128 + j - 256];
}

// ---------------------------------------------------------------------------
// bf16 MFMA GEMM: C[M,N] = A[M,K](bf16) @ BT[N,K](bf16)^T + bias (fp32)
// 128x128 tile, BK=64 staged as two 32-halves (keeps 64B LDS row stride),
// 256 thr = 4 waves (2x2 of 64x64), 16x16x32 MFMA, 32 MFMA per barrier pair.
// Output: bf16 to Cb (stride Nn) if Cb!=null; else fp32 split:
//   col<Nsplit -> Cf[row*Nsplit+col], else Cf2[row*(Nn-Nsplit)+col-Nsplit].
// ---------------------------------------------------------------------------
__global__ __launch_bounds__(256) void gemm_bf16_kernel(
    const ushort_t* __restrict__ A, const ushort_t* __restrict__ BT,
    const float* __restrict__ bias,
    ushort_t* __restrict__ Cb, float* __restrict__ Cf, float* __restrict__ Cf2,
    int M, int Nn, int K, int Nsplit, int relu)
{
    __shared__ ushort_t Alds[2][128*32];
    __shared__ ushort_t Blds[2][128*32];
    const int tid  = threadIdx.x;
    const int wave = tid >> 6, lane = tid & 63;
    const int bm = blockIdx.y * 128, bn = blockIdx.x * 128;
    const int wm = (wave >> 1) * 64, wn = (wave & 1) * 64;

    // staging: 8 chunks of 16 rows x 32 cols (1024B) per matrix-half
    const int c0 = wave * 2, c1 = wave * 2 + 1;
    const int rIn = lane >> 2;
    const int cIn = (lane & 3) * 8;
    const ushort_t* Ag0 = A  + (size_t)(bm + c0*16 + rIn) * K + cIn;
    const ushort_t* Ag1 = A  + (size_t)(bm + c1*16 + rIn) * K + cIn;
    const ushort_t* Bg0 = BT + (size_t)(bn + c0*16 + rIn) * K + cIn;
    const ushort_t* Bg1 = BT + (size_t)(bn + c1*16 + rIn) * K + cIn;

    const int fm    = lane & 15;
    const int quad8 = (lane >> 4) * 8;

    f32x4 acc[4][4];
#pragma unroll
    for (int i = 0; i < 4; i++)
#pragma unroll
        for (int j = 0; j < 4; j++) acc[i][j] = (f32x4){0.f,0.f,0.f,0.f};

    for (int k0 = 0; k0 < K; k0 += 64) {
        gload16(Ag0 + k0,      &Alds[0][c0*512]);
        gload16(Ag1 + k0,      &Alds[0][c1*512]);
        gload16(Bg0 + k0,      &Blds[0][c0*512]);
        gload16(Bg1 + k0,      &Blds[0][c1*512]);
        gload16(Ag0 + k0 + 32, &Alds[1][c0*512]);
        gload16(Ag1 + k0 + 32, &Alds[1][c1*512]);
        gload16(Bg0 + k0 + 32, &Blds[1][c0*512]);
        gload16(Bg1 + k0 + 32, &Blds[1][c1*512]);
        __syncthreads();
#pragma unroll
        for (int h = 0; h < 2; h++) {
            bf16x8 af[4], bfr[4];
#pragma unroll
            for (int i = 0; i < 4; i++)
                af[i]  = *(const bf16x8*)&Alds[h][(wm + i*16 + fm) * 32 + quad8];
#pragma unroll
            for (int j = 0; j < 4; j++)
                bfr[j] = *(const bf16x8*)&Blds[h][(wn + j*16 + fm) * 32 + quad8];
#pragma unroll
            for (int i = 0; i < 4; i++)
#pragma unroll
                for (int j = 0; j < 4; j++)
                    acc[i][j] = __builtin_amdgcn_mfma_f32_16x16x32_bf16(af[i], bfr[j], acc[i][j], 0, 0, 0);
        }
        __syncthreads();
    }

    const int rq = (lane >> 4) * 4;
#pragma unroll
    for (int j = 0; j < 4; j++) {
        int col = bn + wn + j*16 + fm;
        float bb = bias[col];
#pragma unroll
        for (int i = 0; i < 4; i++) {
            int row0 = bm + wm + i*16 + rq;
#pragma unroll
            for (int r = 0; r < 4; r++) {
                float v = acc[i][j][r] + bb;
                if (relu) v = fmaxf(v, 0.f);
                if (Cb) {
                    Cb[(size_t)(row0 + r) * Nn + col] = f2b(v);
                } else if (col < Nsplit) {
                    Cf[(size_t)(row0 + r) * Nsplit + col] = v;
                } else {
                    Cf2[(size_t)(row0 + r) * (Nn - Nsplit) + (col - Nsplit)] = v;
                }
            }
        }
    }
}

// ---------------------------------------------------------------------------
// x = LN(x + res_bf16)*g + b; writes X fp32, Xb bf16, optional Qb=bf16(x+posb)
// ---------------------------------------------------------------------------
__global__ __launch_bounds__(256) void ln_residual_kernel(
    float* __restrict__ x, const ushort_t* __restrict__ res,
    const float* __restrict__ g, const float* __restrict__ bta,
    ushort_t* __restrict__ xb, const ushort_t* __restrict__ posb,
    ushort_t* __restrict__ qb)
{
    int row  = blockIdx.x * 4 + (threadIdx.x >> 6);
    int lane = threadIdx.x & 63;
    size_t base = (size_t)row * C_ + lane * 4;
    float4  xv = *(const float4*)(x + base);
    ushort4 rv = *(const ushort4*)(res + base);
    float v0 = xv.x + b2f(rv.x), v1 = xv.y + b2f(rv.y);
    float v2 = xv.z + b2f(rv.z), v3 = xv.w + b2f(rv.w);
    float s  = v0 + v1 + v2 + v3;
    float s2 = v0*v0 + v1*v1 + v2*v2 + v3*v3;
#pragma unroll
    for (int off = 1; off < 64; off <<= 1) {
        s  += __shfl_xor(s,  off, 64);
        s2 += __shfl_xor(s2, off, 64);
    }
    float mu  = s * (1.f / C_);
    float var = s2 * (1.f / C_) - mu * mu;
    float rs  = rsqrtf(var + 1e-5f);
    float4 gv = *(const float4*)(g + lane * 4);
    float4 bv = *(const float4*)(bta + lane * 4);
    float4 o;
    o.x = (v0 - mu) * rs * gv.x + bv.x;
    o.y = (v1 - mu) * rs * gv.y + bv.y;
    o.z = (v2 - mu) * rs * gv.z + bv.z;
    o.w = (v3 - mu) * rs * gv.w + bv.w;
    *(float4*)(x + base) = o;
    ushort4 ob; ob.x = f2b(o.x); ob.y = f2b(o.y); ob.z = f2b(o.z); ob.w = f2b(o.w);
    *(ushort4*)(xb + base) = ob;
    if (qb) {
        ushort4 pv = *(const ushort4*)(posb + base);
        ushort4 qv;
        qv.x = f2b(o.x + b2f(pv.x)); qv.y = f2b(o.y + b2f(pv.y));
        qv.z = f2b(o.z + b2f(pv.z)); qv.w = f2b(o.w + b2f(pv.w));
        *(ushort4*)(qb + base) = qv;
    }
}

// ---------------------------------------------------------------------------
// Deformable sampling, 2-phase. Block = 128 thr per query.
// Phase 1: thread = (head,pt): softmax + fold attn*bilinear*valid into
//          (byte-offset, weight) int2 pairs in LDS.
// Phase 2: thread = (head, dim-pair): 64 gathers of bf16x2, b64 LDS reads.
// ---------------------------------------------------------------------------
__global__ __launch_bounds__(128) void msdeform_kernel(
    const ushort_t* __restrict__ VALb, const float* __restrict__ OFF,
    const float* __restrict__ ATT, ushort_t* __restrict__ SAMPb)
{
    const int bn = blockIdx.x;
    const int b = bn / N_;
    const int n = bn - b * N_;
    const int tid = threadIdx.x;

    __shared__ int2 s_wi[128 * 4];

    {   // phase 1 — head = tid>>4, li = (tid>>2)&3, p = tid&3
        const int head = tid >> 4, li = (tid >> 2) & 3;
        float logit = ATT[(size_t)bn * 128 + tid];
        float ox = OFF[(size_t)bn * 256 + tid * 2 + 0];
        float oy = OFF[(size_t)bn * 256 + tid * 2 + 1];
        float mx = logit;
#pragma unroll
        for (int s = 1; s < 16; s <<= 1) mx = fmaxf(mx, __shfl_xor(mx, s, 16));
        float e = __expf(logit - mx), sm = e;
#pragma unroll
        for (int s = 1; s < 16; s <<= 1) sm += __shfl_xor(sm, s, 16);
        float aw = e / sm;

        int sq, lwq;
        if      (n < 16384){ sq = 0;     lwq = 7; }
        else if (n < 20480){ sq = 16384; lwq = 6; }
        else if (n < 21504){ sq = 20480; lwq = 5; }
        else               { sq = 21504; lwq = 4; }
        int pidx = n - sq;
        int prow = pidx >> lwq, pcol = pidx & ((1 << lwq) - 1);
        float inv = 1.f / (float)(1 << lwq);
        float refx = (pcol + 0.5f) * inv;
        float refy = (prow + 0.5f) * inv;

        const int HS[4] = {128, 64, 32, 16};
        const int ST[4] = {0, 16384, 20480, 21504};
        int wl = HS[li], st = ST[li];
        float fw = (float)wl;
        float xx = refx * fw + ox - 0.5f;   // (refx + ox/w)*w - 0.5
        float yy = refy * fw + oy - 0.5f;
        float xf = floorf(xx), yf = floorf(yy);
        float wx = xx - xf, wy = yy - yf;
        int x0 = (int)xf, y0 = (int)yf;
#pragma unroll
        for (int c2 = 0; c2 < 4; c2++) {
            int dx = c2 & 1, dy = c2 >> 1;
            int xi = x0 + dx, yi = y0 + dy;
            float wgt = (dx ? wx : 1.f - wx) * (dy ? wy : 1.f - wy);
            bool valid = (xi >= 0) & (xi < wl) & (yi >= 0) & (yi < wl);
            int xc = min(max(xi, 0), wl - 1), yc = min(max(yi, 0), wl - 1);
            int2 wi;
            wi.x = ((st + yc * wl + xc) * C_ + head * 32) * 2;   // byte offset
            wi.y = __float_as_int(valid ? aw * wgt : 0.f);
            s_wi[tid * 4 + c2] = wi;
        }
    }
    __syncthreads();

    const int head = tid >> 4, e2 = (tid & 15) * 2;
    const char* vb = (const char*)VALb + ((size_t)b * N_ * C_ + e2) * 2;
    const int base2 = head * 64;
    float a0 = 0.f, a1 = 0.f;
#pragma unroll 8
    for (int j = 0; j < 64; j++) {
        int2 wi = s_wi[base2 + j];
        float w = __int_as_float(wi.y);
        ushort2 u = *(const ushort2*)(vb + wi.x);
        a0 += w * b2f(u.x);
        a1 += w * b2f(u.y);
    }
    ushort2 o2; o2.x = f2b(a0); o2.y = f2b(a1);
    *(ushort2*)(SAMPb + (size_t)bn * C_ + head * 32 + e2) = o2;
}

// ---------------------------------------------------------------------------
// Workspace (bytes), ~185.3 MB:
//   POSB bf16 22.28M | OFFf f32 44.56M | ATTf f32 22.28M | SAMPB bf16 22.28M |
//   VALB bf16 22.28M | XB 22.28M | QB 22.28M | WT bf16 9.04M | PB 9216B
//   FFN hidden HB (bf16, M*1024) overlays [OFFf|ATTf|SAMPB] exactly.
//   VALB also hosts attn-out and FFN-out (dead-time reuse).
// ---------------------------------------------------------------------------
extern "C" void kernel_launch(void* const* d_in, const int* in_sizes, int n_in,
                              void* d_out, int out_size, void* d_ws, size_t ws_size,
                              hipStream_t stream)
{
    const float *srcs[4], *poss[4];
    if (in_sizes[1] == in_sizes[0]) {   // interleaved src0,pos0,src1,pos1,...
        srcs[0] = (const float*)d_in[0]; poss[0] = (const float*)d_in[1];
        srcs[1] = (const float*)d_in[2]; poss[1] = (const float*)d_in[3];
        srcs[2] = (const float*)d_in[4]; poss[2] = (const float*)d_in[5];
        srcs[3] = (const float*)d_in[6]; poss[3] = (const float*)d_in[7];
    } else {
        srcs[0] = (const float*)d_in[0]; srcs[1] = (const float*)d_in[1];
        srcs[2] = (const float*)d_in[2]; srcs[3] = (const float*)d_in[3];
        poss[0] = (const float*)d_in[4]; poss[1] = (const float*)d_in[5];
        poss[2] = (const float*)d_in[6]; poss[3] = (const float*)d_in[7];
    }
    const float* le = (const float*)d_in[8];

    float* X = (float*)d_out;
    char* w = (char*)d_ws;
    ushort_t* POSB  = (ushort_t*)w;           w += (size_t)M_ * C_ * 2;
    float*    OFFf  = (float*)w;              w += (size_t)M_ * C_ * 4;
    float*    ATTf  = (float*)w;              w += (size_t)M_ * 128 * 4;
    ushort_t* SAMPB = (ushort_t*)w;           w += (size_t)M_ * C_ * 2;
    ushort_t* VALB  = (ushort_t*)w;           w += (size_t)M_ * C_ * 2;
    ushort_t* XB    = (ushort_t*)w;           w += (size_t)M_ * C_ * 2;
    ushort_t* QB    = (ushort_t*)w;           w += (size_t)M_ * C_ * 2;
    ushort_t* WT    = (ushort_t*)w;           w += (size_t)6 * 753664 * 2;
    float*    PB    = (float*)w;
    ushort_t* HB    = (ushort_t*)OFFf;        // overlays OFFf|ATTf|SAMPB exactly

    // per-layer WT element offsets ([val][off|att packed][out][ff1][ff2])
    const long LSTRIDE = 753664;
    const long O_WVAL = 0, O_WOFF = 65536, O_WATT = 131072, O_WOUT = 163840,
               O_WF1 = 229376, O_WF2 = 491520;

    wprep_kernel<<<6*65536/256, 256, 0, stream>>>((const float*)d_in[13], WT + O_WVAL, 256, 256,  LSTRIDE);
    wprep_kernel<<<6*65536/256, 256, 0, stream>>>((const float*)d_in[9],  WT + O_WOFF, 256, 256,  LSTRIDE);
    wprep_kernel<<<6*32768/256, 256, 0, stream>>>((const float*)d_in[11], WT + O_WATT, 256, 128,  LSTRIDE);
    wprep_kernel<<<6*65536/256, 256, 0, stream>>>((const float*)d_in[15], WT + O_WOUT, 256, 256,  LSTRIDE);
    wprep_kernel<<<6*262144/256,256, 0, stream>>>((const float*)d_in[19], WT + O_WF1,  256, 1024, LSTRIDE);
    wprep_kernel<<<6*262144/256,256, 0, stream>>>((const float*)d_in[21], WT + O_WF2,  1024, 256, LSTRIDE);
    bias_pack_kernel<<<9, 256, 0, stream>>>((const float*)d_in[10], (const float*)d_in[12], PB);

    concat_init_kernel<<<2*5440, 256, 0, stream>>>(srcs[0], srcs[1], srcs[2], srcs[3],
                                                   poss[0], poss[1], poss[2], poss[3],
                                                   le, X, POSB, XB, QB);

    for (int l = 0; l < L_; l++) {
        const ushort_t* wt = WT + (size_t)l * LSTRIDE;
        const float* bval = (const float*)d_in[14] + (size_t)l * C_;
        const float* bout = (const float*)d_in[16] + (size_t)l * C_;
        const float* g1   = (const float*)d_in[17] + (size_t)l * C_;
        const float* b1   = (const float*)d_in[18] + (size_t)l * C_;
        const float* bf1  = (const float*)d_in[20] + (size_t)l * F_;
        const float* bf2  = (const float*)d_in[22] + (size_t)l * C_;
        const float* g2   = (const float*)d_in[23] + (size_t)l * C_;
        const float* b2   = (const float*)d_in[24] + (size_t)l * C_;

        gemm_bf16_kernel<<<dim3(2, M_/128), 256, 0, stream>>>(XB, wt + O_WVAL, bval,
            VALB, nullptr, nullptr, M_, 256, 256, 256, 0);
        // fused offset+attn projection: N=384 (cols 0:256 -> OFFf, 256:384 -> ATTf)
        gemm_bf16_kernel<<<dim3(3, M_/128), 256, 0, stream>>>(QB, wt + O_WOFF, PB + (size_t)l*384,
            nullptr, OFFf, ATTf, M_, 384, 256, 256, 0);
        msdeform_kernel<<<M_, 128, 0, stream>>>(VALB, OFFf, ATTf, SAMPB);
        gemm_bf16_kernel<<<dim3(2, M_/128), 256, 0, stream>>>(SAMPB, wt + O_WOUT, bout,
            VALB, nullptr, nullptr, M_, 256, 256, 256, 0);
        ln_residual_kernel<<<M_/4, 256, 0, stream>>>(X, VALB, g1, b1, XB, nullptr, nullptr);
        gemm_bf16_kernel<<<dim3(8, M_/128), 256, 0, stream>>>(XB, wt + O_WF1, bf1,
            HB, nullptr, nullptr, M_, 1024, 256, 1024, 1);
        gemm_bf16_kernel<<<dim3(2, M_/128), 256, 0, stream>>>(HB, wt + O_WF2, bf2,
            VALB, nullptr, nullptr, M_, 256, 1024, 256, 0);
        ln_residual_kernel<<<M_/4, 256, 0, stream>>>(X, VALB, g2, b2, XB, POSB, QB);
    }
}